// Round 5
// baseline (131.541 us; speedup 1.0000x reference)
//
#include <hip/hip_runtime.h>

#define VIEWS 512
#define DETS  512
#define HH    256
#define WW    256
#define NS    384
#define P     264   // 2-ring zero pad (+ slack): valid pixel (y,x) at [y+2][x+2]

typedef float4 float4_a8 __attribute__((aligned(8)));

// Padded interleaved image: L[r][c] = (ch0, ch1) at pixel (y=r-2, x=c-2), zero outside.
__global__ void build_padded(const float* __restrict__ img, float2* __restrict__ L) {
    int i = blockIdx.x * blockDim.x + threadIdx.x;
    if (i >= P * P) return;
    int r = i / P, c = i - r * P;
    int y = r - 2, x = c - 2;
    float2 val = make_float2(0.0f, 0.0f);
    if (x >= 0 && x < WW && y >= 0 && y < HH) {
        int k = y * WW + x;
        val = make_float2(img[k], img[HH * WW + k]);
    }
    L[i] = val;
}

// Wave = 8 dets x 8 sample-slots. Thread (det_l, slot) samples s = sb+slot, +8, ...
// Wave footprint per iteration: ~4px (det dir) x ~8px (ray dir) compact patch.
__global__ __launch_bounds__(256) void project_tile(
    const float2* __restrict__ img2,
    const float* __restrict__ opt,
    float* __restrict__ out)
{
    int tid  = threadIdx.x;
    int wave = tid >> 6;        // 0..3
    int lane = tid & 63;
    int det_l = lane & 7;       // 0..7
    int slot  = lane >> 3;      // 0..7

    int det_base = blockIdx.x * 32 + wave * 8;
    int j = det_base + det_l;   // detector
    int v = blockIdx.y;         // view

    float dImg = opt[4], dDet = opt[5], ang0 = opt[6], dAng = opt[7];
    float s2r = opt[8], d2r = opt[9], binshift = opt[10];

    float beta = ang0 + dAng * (float)v;
    float cb = cosf(beta), sb = sinf(beta);
    float u = ((float)j - (DETS - 1) * 0.5f) * dDet + binshift;

    float srcx = s2r * cb, srcy = s2r * sb;
    float dx = -d2r * cb - u * sb - srcx;
    float dy = -d2r * sb + u * cb - srcy;
    float inv = rsqrtf(dx * dx + dy * dy);
    dx *= inv; dy *= inv;

    float R  = 0.5f * sqrtf((float)(HH * HH + WW * WW)) * dImg;
    float dl = 2.0f * R / (float)NS;
    float t0 = s2r - R + 0.5f * dl;
    float invD = 1.0f / dImg;

    float px0 = (srcx + dx * t0) * invD + (WW - 1) * 0.5f;
    float py0 = (srcy + dy * t0) * invD + (HH - 1) * 0.5f;
    float sx = dx * dl * invD;
    float sy = dy * dl * invD;

    // Analytic sample range: reference contributes iff px in (-1,W) AND py in (-1,H).
    // Conservative by <=1 sample each side; slack samples read only the zero pad.
    float lo = 0.0f, hi = (float)(NS - 1);
    if (fabsf(sx) > 1e-7f) {
        float a = (-1.0f - px0) / sx, b = ((float)WW - px0) / sx;
        lo = fmaxf(lo, fminf(a, b)); hi = fminf(hi, fmaxf(a, b));
    } else if (!(px0 > -1.0f && px0 < (float)WW)) { lo = 1.0f; hi = 0.0f; }
    if (fabsf(sy) > 1e-7f) {
        float a = (-1.0f - py0) / sy, b = ((float)HH - py0) / sy;
        lo = fmaxf(lo, fminf(a, b)); hi = fminf(hi, fmaxf(a, b));
    } else if (!(py0 > -1.0f && py0 < (float)HH)) { lo = 1.0f; hi = 0.0f; }
    lo = fminf(fmaxf(lo, 0.0f), (float)NS);
    hi = fminf(fmaxf(hi, 0.0f), (float)NS);

    int s_begin = max((int)floorf(lo), 0);
    int s_end   = min((int)ceilf(hi) + 1, NS);

    float acc0 = 0.0f, acc1 = 0.0f;

    for (int s = s_begin + slot; s < s_end; s += 8) {
        float px = fmaf((float)s, sx, px0);
        float py = fmaf((float)s, sy, py0);
        float xf = floorf(px), yf = floorf(py);
        float wx = px - xf, wy = py - yf;
        // Clamp into the provable pad range: any clamped access reads zeros only.
        int x0p = min(max((int)xf + 2, 0), P - 3);
        int y0p = min(max((int)yf + 2, 0), P - 2);

        const float2* r0 = img2 + (y0p * P + x0p);
        float4 q0 = *(const float4_a8*)r0;        // (v00.c0 v00.c1 v01.c0 v01.c1)
        float4 q1 = *(const float4_a8*)(r0 + P);  // (v10.c0 v10.c1 v11.c0 v11.c1)

        float ax = 1.0f - wx, ay = 1.0f - wy;
        float w00 = ax * ay, w01 = wx * ay;
        float w10 = ax * wy, w11 = wx * wy;

        acc0 = fmaf(w00, q0.x, acc0);
        acc1 = fmaf(w00, q0.y, acc1);
        acc0 = fmaf(w01, q0.z, acc0);
        acc1 = fmaf(w01, q0.w, acc1);
        acc0 = fmaf(w10, q1.x, acc0);
        acc1 = fmaf(w10, q1.y, acc1);
        acc0 = fmaf(w11, q1.z, acc0);
        acc1 = fmaf(w11, q1.w, acc1);
    }

    // Sum over the 8 sample-slots (lane bits 3..5). All lanes participate.
    acc0 += __shfl_xor(acc0, 8);
    acc1 += __shfl_xor(acc1, 8);
    acc0 += __shfl_xor(acc0, 16);
    acc1 += __shfl_xor(acc1, 16);
    acc0 += __shfl_xor(acc0, 32);
    acc1 += __shfl_xor(acc1, 32);

    if (lane < 8) {
        int o = v * DETS + det_base + lane;
        out[o] = acc0 * dl;
        out[VIEWS * DETS + o] = acc1 * dl;
    }
}

// Fallback (ws too small): one thread per ray, planar loads, direct store.
__global__ __launch_bounds__(256) void project_fallback(
    const float* __restrict__ img,
    const float* __restrict__ opt,
    float* __restrict__ out)
{
    int idx = blockIdx.x * blockDim.x + threadIdx.x;
    int v = idx >> 9;
    int j = idx & (DETS - 1);

    float dImg = opt[4], dDet = opt[5], ang0 = opt[6], dAng = opt[7];
    float s2r = opt[8], d2r = opt[9], binshift = opt[10];

    float beta = ang0 + dAng * (float)v;
    float cb = cosf(beta), sb = sinf(beta);
    float u = ((float)j - (DETS - 1) * 0.5f) * dDet + binshift;

    float srcx = s2r * cb, srcy = s2r * sb;
    float dx = -d2r * cb - u * sb - srcx;
    float dy = -d2r * sb + u * cb - srcy;
    float inv = rsqrtf(dx * dx + dy * dy);
    dx *= inv; dy *= inv;

    float R  = 0.5f * sqrtf((float)(HH * HH + WW * WW)) * dImg;
    float dl = 2.0f * R / (float)NS;
    float t0 = s2r - R + 0.5f * dl;
    float invD = 1.0f / dImg;

    float px0 = (srcx + dx * t0) * invD + (WW - 1) * 0.5f;
    float py0 = (srcy + dy * t0) * invD + (HH - 1) * 0.5f;
    float sx = dx * dl * invD;
    float sy = dy * dl * invD;

    float acc0 = 0.0f, acc1 = 0.0f;
    for (int s = 0; s < NS; ++s) {
        float px = fmaf((float)s, sx, px0);
        float py = fmaf((float)s, sy, py0);
        if (px > -1.0f && px < (float)WW && py > -1.0f && py < (float)HH) {
            float x0 = floorf(px), y0 = floorf(py);
            float wx = px - x0, wy = py - y0;
            int x0i = (int)x0, y0i = (int)y0;
            int x1i = x0i + 1, y1i = y0i + 1;
            bool bx0 = (x0i >= 0), bx1 = (x1i <= WW - 1);
            bool by0 = (y0i >= 0), by1 = (y1i <= HH - 1);
            int xc0 = bx0 ? x0i : 0, xc1 = bx1 ? x1i : (WW - 1);
            int yc0 = by0 ? y0i : 0, yc1 = by1 ? y1i : (HH - 1);
            float w00 = (1.0f - wx) * (1.0f - wy);
            float w01 = wx * (1.0f - wy);
            float w10 = (1.0f - wx) * wy;
            float w11 = wx * wy;
            w00 = (bx0 & by0) ? w00 : 0.0f;
            w01 = (bx1 & by0) ? w01 : 0.0f;
            w10 = (bx0 & by1) ? w10 : 0.0f;
            w11 = (bx1 & by1) ? w11 : 0.0f;
            int r0 = yc0 * WW, r1 = yc1 * WW;
            const float* p0 = img;
            const float* p1 = img + HH * WW;
            acc0 = fmaf(w00, p0[r0 + xc0], acc0);
            acc0 = fmaf(w01, p0[r0 + xc1], acc0);
            acc0 = fmaf(w10, p0[r1 + xc0], acc0);
            acc0 = fmaf(w11, p0[r1 + xc1], acc0);
            acc1 = fmaf(w00, p1[r0 + xc0], acc1);
            acc1 = fmaf(w01, p1[r0 + xc1], acc1);
            acc1 = fmaf(w10, p1[r1 + xc0], acc1);
            acc1 = fmaf(w11, p1[r1 + xc1], acc1);
        }
    }
    int o = v * DETS + j;
    out[o] = acc0 * dl;
    out[VIEWS * DETS + o] = acc1 * dl;
}

extern "C" void kernel_launch(void* const* d_in, const int* in_sizes, int n_in,
                              void* d_out, int out_size, void* d_ws, size_t ws_size,
                              hipStream_t stream) {
    const float* img = (const float*)d_in[0];
    const float* opt = (const float*)d_in[1];
    float* out = (float*)d_out;

    size_t need = sizeof(float2) * P * P;
    if (ws_size >= need) {
        float2* L = (float2*)d_ws;
        build_padded<<<(P * P + 255) / 256, 256, 0, stream>>>(img, L);
        dim3 grid(DETS / 32, VIEWS);  // 4 waves/block, 8 dets/wave
        project_tile<<<grid, 256, 0, stream>>>(L, opt, out);
    } else {
        project_fallback<<<VIEWS * DETS / 256, 256, 0, stream>>>(img, opt, out);
    }
}

// Round 6
// 91.202 us; speedup vs baseline: 1.4423x; 1.4423x over previous
//
#include <hip/hip_runtime.h>

#define VIEWS 512
#define DETS  512
#define HH    256
#define WW    256
#define NS    384
#define P     264   // entry grid: entry[r][c] covers pixels (r-2..r-1, c-2..c-1); zero outside

// Pack two floats as bf16 (RNE) into one dword: lo = a, hi = b.
__device__ inline unsigned bf16pair(float a, float b) {
    unsigned ua = __float_as_uint(a);
    ua = (ua + 0x7fffu + ((ua >> 16) & 1u)) >> 16;
    unsigned ub = __float_as_uint(b);
    ub = (ub + 0x7fffu + ((ub >> 16) & 1u)) >> 16;
    return ua | (ub << 16);
}

// Build packed bilinear-quad entries. N: normal orientation. T: transposed (optional).
// Entry = (v00c0,v00c1 | v01c0,v01c1 | v10c0,v10c1 | v11c0,v11c1) as 8 x bf16.
__global__ void build_pack(const float* __restrict__ img,
                           uint4* __restrict__ N, uint4* __restrict__ T) {
    int i = blockIdx.x * blockDim.x + threadIdx.x;
    if (i >= P * P) return;
    int r = i / P, c = i - r * P;
    int y = r - 2, x = c - 2;

    auto g = [&](int yy, int xx, int ch) -> float {
        return (xx >= 0 && xx < WW && yy >= 0 && yy < HH)
             ? img[ch * HH * WW + yy * WW + xx] : 0.0f;
    };

    uint4 e;
    e.x = bf16pair(g(y,     x,     0), g(y,     x,     1));
    e.y = bf16pair(g(y,     x + 1, 0), g(y,     x + 1, 1));
    e.z = bf16pair(g(y + 1, x,     0), g(y + 1, x,     1));
    e.w = bf16pair(g(y + 1, x + 1, 0), g(y + 1, x + 1, 1));
    N[i] = e;

    if (T) {
        // Timg(a,b) = img(b,a). Entry pixels: Timg(y..y+1, x..x+1).
        uint4 t;
        t.x = bf16pair(g(x,     y,     0), g(x,     y,     1));
        t.y = bf16pair(g(x + 1, y,     0), g(x + 1, y,     1));
        t.z = bf16pair(g(x,     y + 1, 0), g(x,     y + 1, 1));
        t.w = bf16pair(g(x + 1, y + 1, 0), g(x + 1, y + 1, 1));
        T[i] = t;
    }
}

// Wave = 8 dets x 8 sample-slots; one dwordx4 gather per sample.
__global__ __launch_bounds__(256) void project_pack(
    const uint4* __restrict__ imgN,
    const uint4* __restrict__ imgT,
    int allow_trans,
    const float* __restrict__ opt,
    float* __restrict__ out)
{
    int tid  = threadIdx.x;
    int wave = tid >> 6;
    int lane = tid & 63;
    int det_l = lane & 7;
    int slot  = lane >> 3;

    int det_base = blockIdx.x * 32 + wave * 8;
    int j = det_base + det_l;
    int v = blockIdx.y;

    float dImg = opt[4], dDet = opt[5], ang0 = opt[6], dAng = opt[7];
    float s2r = opt[8], d2r = opt[9], binshift = opt[10];

    float beta = ang0 + dAng * (float)v;
    float cb = cosf(beta), sb = sinf(beta);
    float u = ((float)j - (DETS - 1) * 0.5f) * dDet + binshift;

    float srcx = s2r * cb, srcy = s2r * sb;
    float dx = -d2r * cb - u * sb - srcx;
    float dy = -d2r * sb + u * cb - srcy;
    float inv = rsqrtf(dx * dx + dy * dy);
    dx *= inv; dy *= inv;

    float R  = 0.5f * sqrtf((float)(HH * HH + WW * WW)) * dImg;
    float dl = 2.0f * R / (float)NS;
    float t0 = s2r - R + 0.5f * dl;
    float invD = 1.0f / dImg;

    float px0 = (srcx + dx * t0) * invD + (WW - 1) * 0.5f;
    float py0 = (srcy + dy * t0) * invD + (HH - 1) * 0.5f;
    float sx = dx * dl * invD;
    float sy = dy * dl * invD;

    // Pick orientation where det-spread is row-aligned (slope <= 1).
    bool trans = allow_trans && (fabsf(cb) > fabsf(sb));
    const uint4* img2 = trans ? imgT : imgN;
    if (trans) { float t = px0; px0 = py0; py0 = t; t = sx; sx = sy; sy = t; }

    // Analytic sample range; slack samples land in the zero border. Conservative <=1 each side.
    float lo = 0.0f, hi = (float)(NS - 1);
    if (fabsf(sx) > 1e-7f) {
        float a = (-1.0f - px0) / sx, b = ((float)WW - px0) / sx;
        lo = fmaxf(lo, fminf(a, b)); hi = fminf(hi, fmaxf(a, b));
    } else if (!(px0 > -1.0f && px0 < (float)WW)) { lo = 1.0f; hi = 0.0f; }
    if (fabsf(sy) > 1e-7f) {
        float a = (-1.0f - py0) / sy, b = ((float)HH - py0) / sy;
        lo = fmaxf(lo, fminf(a, b)); hi = fminf(hi, fmaxf(a, b));
    } else if (!(py0 > -1.0f && py0 < (float)HH)) { lo = 1.0f; hi = 0.0f; }
    lo = fminf(fmaxf(lo, 0.0f), (float)NS);
    hi = fminf(fmaxf(hi, 0.0f), (float)NS);

    int s_begin = max((int)floorf(lo), 0);
    int s_end   = min((int)ceilf(hi) + 1, NS);

    float acc0 = 0.0f, acc1 = 0.0f;

    #pragma unroll 2
    for (int s = s_begin + slot; s < s_end; s += 8) {
        float px = fmaf((float)s, sx, px0);
        float py = fmaf((float)s, sy, py0);
        float xf = floorf(px), yf = floorf(py);
        float wx = px - xf, wy = py - yf;
        int x0p = min(max((int)xf + 2, 0), P - 1);
        int y0p = min(max((int)yf + 2, 0), P - 1);

        uint4 e = img2[y0p * P + x0p];

        float ax = 1.0f - wx, ay = 1.0f - wy;
        float w00 = ax * ay, w01 = wx * ay;
        float w10 = ax * wy, w11 = wx * wy;

        acc0 = fmaf(w00, __uint_as_float(e.x << 16),          acc0);
        acc1 = fmaf(w00, __uint_as_float(e.x & 0xffff0000u),  acc1);
        acc0 = fmaf(w01, __uint_as_float(e.y << 16),          acc0);
        acc1 = fmaf(w01, __uint_as_float(e.y & 0xffff0000u),  acc1);
        acc0 = fmaf(w10, __uint_as_float(e.z << 16),          acc0);
        acc1 = fmaf(w10, __uint_as_float(e.z & 0xffff0000u),  acc1);
        acc0 = fmaf(w11, __uint_as_float(e.w << 16),          acc0);
        acc1 = fmaf(w11, __uint_as_float(e.w & 0xffff0000u),  acc1);
    }

    acc0 += __shfl_xor(acc0, 8);
    acc1 += __shfl_xor(acc1, 8);
    acc0 += __shfl_xor(acc0, 16);
    acc1 += __shfl_xor(acc1, 16);
    acc0 += __shfl_xor(acc0, 32);
    acc1 += __shfl_xor(acc1, 32);

    if (lane < 8) {
        int o = v * DETS + det_base + lane;
        out[o] = acc0 * dl;
        out[VIEWS * DETS + o] = acc1 * dl;
    }
}

// Fallback (ws too small): one thread per ray, planar loads, direct store.
__global__ __launch_bounds__(256) void project_fallback(
    const float* __restrict__ img,
    const float* __restrict__ opt,
    float* __restrict__ out)
{
    int idx = blockIdx.x * blockDim.x + threadIdx.x;
    int v = idx >> 9;
    int j = idx & (DETS - 1);

    float dImg = opt[4], dDet = opt[5], ang0 = opt[6], dAng = opt[7];
    float s2r = opt[8], d2r = opt[9], binshift = opt[10];

    float beta = ang0 + dAng * (float)v;
    float cb = cosf(beta), sb = sinf(beta);
    float u = ((float)j - (DETS - 1) * 0.5f) * dDet + binshift;

    float srcx = s2r * cb, srcy = s2r * sb;
    float dx = -d2r * cb - u * sb - srcx;
    float dy = -d2r * sb + u * cb - srcy;
    float inv = rsqrtf(dx * dx + dy * dy);
    dx *= inv; dy *= inv;

    float R  = 0.5f * sqrtf((float)(HH * HH + WW * WW)) * dImg;
    float dl = 2.0f * R / (float)NS;
    float t0 = s2r - R + 0.5f * dl;
    float invD = 1.0f / dImg;

    float px0 = (srcx + dx * t0) * invD + (WW - 1) * 0.5f;
    float py0 = (srcy + dy * t0) * invD + (HH - 1) * 0.5f;
    float sx = dx * dl * invD;
    float sy = dy * dl * invD;

    float acc0 = 0.0f, acc1 = 0.0f;
    for (int s = 0; s < NS; ++s) {
        float px = fmaf((float)s, sx, px0);
        float py = fmaf((float)s, sy, py0);
        if (px > -1.0f && px < (float)WW && py > -1.0f && py < (float)HH) {
            float x0 = floorf(px), y0 = floorf(py);
            float wx = px - x0, wy = py - y0;
            int x0i = (int)x0, y0i = (int)y0;
            int x1i = x0i + 1, y1i = y0i + 1;
            bool bx0 = (x0i >= 0), bx1 = (x1i <= WW - 1);
            bool by0 = (y0i >= 0), by1 = (y1i <= HH - 1);
            int xc0 = bx0 ? x0i : 0, xc1 = bx1 ? x1i : (WW - 1);
            int yc0 = by0 ? y0i : 0, yc1 = by1 ? y1i : (HH - 1);
            float w00 = (1.0f - wx) * (1.0f - wy);
            float w01 = wx * (1.0f - wy);
            float w10 = (1.0f - wx) * wy;
            float w11 = wx * wy;
            w00 = (bx0 & by0) ? w00 : 0.0f;
            w01 = (bx1 & by0) ? w01 : 0.0f;
            w10 = (bx0 & by1) ? w10 : 0.0f;
            w11 = (bx1 & by1) ? w11 : 0.0f;
            int r0 = yc0 * WW, r1 = yc1 * WW;
            const float* p0 = img;
            const float* p1 = img + HH * WW;
            acc0 = fmaf(w00, p0[r0 + xc0], acc0);
            acc0 = fmaf(w01, p0[r0 + xc1], acc0);
            acc0 = fmaf(w10, p0[r1 + xc0], acc0);
            acc0 = fmaf(w11, p0[r1 + xc1], acc0);
            acc1 = fmaf(w00, p1[r0 + xc0], acc1);
            acc1 = fmaf(w01, p1[r0 + xc1], acc1);
            acc1 = fmaf(w10, p1[r1 + xc0], acc1);
            acc1 = fmaf(w11, p1[r1 + xc1], acc1);
        }
    }
    int o = v * DETS + j;
    out[o] = acc0 * dl;
    out[VIEWS * DETS + o] = acc1 * dl;
}

extern "C" void kernel_launch(void* const* d_in, const int* in_sizes, int n_in,
                              void* d_out, int out_size, void* d_ws, size_t ws_size,
                              hipStream_t stream) {
    const float* img = (const float*)d_in[0];
    const float* opt = (const float*)d_in[1];
    float* out = (float*)d_out;

    size_t one = sizeof(uint4) * P * P;
    dim3 grid(DETS / 32, VIEWS);

    if (ws_size >= 2 * one) {
        uint4* N = (uint4*)d_ws;
        uint4* T = N + P * P;
        build_pack<<<(P * P + 255) / 256, 256, 0, stream>>>(img, N, T);
        project_pack<<<grid, 256, 0, stream>>>(N, T, 1, opt, out);
    } else if (ws_size >= one) {
        uint4* N = (uint4*)d_ws;
        build_pack<<<(P * P + 255) / 256, 256, 0, stream>>>(img, N, nullptr);
        project_pack<<<grid, 256, 0, stream>>>(N, N, 0, opt, out);
    } else {
        project_fallback<<<VIEWS * DETS / 256, 256, 0, stream>>>(img, opt, out);
    }
}

// Round 7
// 62.826 us; speedup vs baseline: 2.0938x; 1.4517x over previous
//
#include <hip/hip_runtime.h>

#define VIEWS 512
#define DETS  512
#define HH    256
#define WW    256
#define NS    384
#define P     264   // entry grid: entry[r][c] covers pixels (r-2..r-1, c-2..c-1); zero outside

// Pack two floats as bf16 (RNE) into one dword: lo = a, hi = b.
__device__ inline unsigned bf16pair(float a, float b) {
    unsigned ua = __float_as_uint(a);
    ua = (ua + 0x7fffu + ((ua >> 16) & 1u)) >> 16;
    unsigned ub = __float_as_uint(b);
    ub = (ub + 0x7fffu + ((ub >> 16) & 1u)) >> 16;
    return ua | (ub << 16);
}

// Build packed bilinear-quad entries. N: normal orientation. T: transposed (optional).
// Entry = (v00c0,v00c1 | v01c0,v01c1 | v10c0,v10c1 | v11c0,v11c1) as 8 x bf16.
__global__ void build_pack(const float* __restrict__ img,
                           uint4* __restrict__ N, uint4* __restrict__ T) {
    int i = blockIdx.x * blockDim.x + threadIdx.x;
    if (i >= P * P) return;
    int r = i / P, c = i - r * P;
    int y = r - 2, x = c - 2;

    auto g = [&](int yy, int xx, int ch) -> float {
        return (xx >= 0 && xx < WW && yy >= 0 && yy < HH)
             ? img[ch * HH * WW + yy * WW + xx] : 0.0f;
    };

    uint4 e;
    e.x = bf16pair(g(y,     x,     0), g(y,     x,     1));
    e.y = bf16pair(g(y,     x + 1, 0), g(y,     x + 1, 1));
    e.z = bf16pair(g(y + 1, x,     0), g(y + 1, x,     1));
    e.w = bf16pair(g(y + 1, x + 1, 0), g(y + 1, x + 1, 1));
    N[i] = e;

    if (T) {
        uint4 t;
        t.x = bf16pair(g(x,     y,     0), g(x,     y,     1));
        t.y = bf16pair(g(x + 1, y,     0), g(x + 1, y,     1));
        t.z = bf16pair(g(x,     y + 1, 0), g(x,     y + 1, 1));
        t.w = bf16pair(g(x + 1, y + 1, 0), g(x + 1, y + 1, 1));
        T[i] = t;
    }
}

__device__ inline float2 fma2(float w, float2 a, float2 c) {
    c.x = fmaf(w, a.x, c.x);
    c.y = fmaf(w, a.y, c.y);
    return c;
}

// Wave = 8 dets x 8 sample-slots; one dwordx4 gather per sample.
// Wave w of block b handles det-group (b + 16*w): every block mixes center+edge work.
__global__ __launch_bounds__(256, 8) void project_pack(
    const uint4* __restrict__ imgN,
    const uint4* __restrict__ imgT,
    int allow_trans,
    const float* __restrict__ opt,
    float* __restrict__ out)
{
    int tid  = threadIdx.x;
    int wave = tid >> 6;
    int lane = tid & 63;
    int det_l = lane & 7;
    int slot  = lane >> 3;

    int det_base = (blockIdx.x + wave * 16) * 8;   // balanced det-group remap
    int j = det_base + det_l;
    int v = blockIdx.y;

    float dImg = opt[4], dDet = opt[5], ang0 = opt[6], dAng = opt[7];
    float s2r = opt[8], d2r = opt[9], binshift = opt[10];

    float beta = ang0 + dAng * (float)v;
    float cb = cosf(beta), sb = sinf(beta);
    float u = ((float)j - (DETS - 1) * 0.5f) * dDet + binshift;

    float srcx = s2r * cb, srcy = s2r * sb;
    float dx = -d2r * cb - u * sb - srcx;
    float dy = -d2r * sb + u * cb - srcy;
    float inv = rsqrtf(dx * dx + dy * dy);
    dx *= inv; dy *= inv;

    float R  = 0.5f * sqrtf((float)(HH * HH + WW * WW)) * dImg;
    float dl = 2.0f * R / (float)NS;
    float t0 = s2r - R + 0.5f * dl;
    float invD = 1.0f / dImg;

    float px0 = (srcx + dx * t0) * invD + (WW - 1) * 0.5f;
    float py0 = (srcy + dy * t0) * invD + (HH - 1) * 0.5f;
    float sx = dx * dl * invD;
    float sy = dy * dl * invD;

    // Pick orientation where det-spread is row-aligned (slope <= 1).
    bool trans = allow_trans && (fabsf(cb) > fabsf(sb));
    const uint4* img2 = trans ? imgT : imgN;
    if (trans) { float t = px0; px0 = py0; py0 = t; t = sx; sx = sy; sy = t; }

    // Analytic sample range; slack samples land in the zero border.
    float lo = 0.0f, hi = (float)(NS - 1);
    if (fabsf(sx) > 1e-7f) {
        float a = (-1.0f - px0) / sx, b = ((float)WW - px0) / sx;
        lo = fmaxf(lo, fminf(a, b)); hi = fminf(hi, fmaxf(a, b));
    } else if (!(px0 > -1.0f && px0 < (float)WW)) { lo = 1.0f; hi = 0.0f; }
    if (fabsf(sy) > 1e-7f) {
        float a = (-1.0f - py0) / sy, b = ((float)HH - py0) / sy;
        lo = fmaxf(lo, fminf(a, b)); hi = fminf(hi, fmaxf(a, b));
    } else if (!(py0 > -1.0f && py0 < (float)HH)) { lo = 1.0f; hi = 0.0f; }
    lo = fminf(fmaxf(lo, 0.0f), (float)NS);
    hi = fminf(fmaxf(hi, 0.0f), (float)NS);

    int s_begin = max((int)floorf(lo), 0);
    int s_end   = min((int)ceilf(hi) + 1, NS);

    float2 acc = make_float2(0.0f, 0.0f);
    float fs = (float)(s_begin + slot);

    #pragma unroll 2
    for (int s = s_begin + slot; s < s_end; s += 8, fs += 8.0f) {
        float px = fmaf(fs, sx, px0);
        float py = fmaf(fs, sy, py0);
        float xf = floorf(px), yf = floorf(py);
        float wx = px - xf, wy = py - yf;
        int x0p = min(max((int)xf + 2, 0), P - 1);
        int y0p = min(max((int)yf + 2, 0), P - 1);

        uint4 e = img2[y0p * P + x0p];

        float2 v00 = make_float2(__uint_as_float(e.x << 16), __uint_as_float(e.x & 0xffff0000u));
        float2 v01 = make_float2(__uint_as_float(e.y << 16), __uint_as_float(e.y & 0xffff0000u));
        float2 v10 = make_float2(__uint_as_float(e.z << 16), __uint_as_float(e.z & 0xffff0000u));
        float2 v11 = make_float2(__uint_as_float(e.w << 16), __uint_as_float(e.w & 0xffff0000u));

        float ax = 1.0f - wx, ay = 1.0f - wy;
        float w00 = ax * ay, w01 = wx * ay;
        float w10 = ax * wy, w11 = wx * wy;

        acc = fma2(w00, v00, acc);
        acc = fma2(w01, v01, acc);
        acc = fma2(w10, v10, acc);
        acc = fma2(w11, v11, acc);
    }

    acc.x += __shfl_xor(acc.x, 8);
    acc.y += __shfl_xor(acc.y, 8);
    acc.x += __shfl_xor(acc.x, 16);
    acc.y += __shfl_xor(acc.y, 16);
    acc.x += __shfl_xor(acc.x, 32);
    acc.y += __shfl_xor(acc.y, 32);

    if (lane < 8) {
        int o = v * DETS + det_base + lane;
        out[o] = acc.x * dl;
        out[VIEWS * DETS + o] = acc.y * dl;
    }
}

// Fallback (ws too small): one thread per ray, planar loads, direct store.
__global__ __launch_bounds__(256) void project_fallback(
    const float* __restrict__ img,
    const float* __restrict__ opt,
    float* __restrict__ out)
{
    int idx = blockIdx.x * blockDim.x + threadIdx.x;
    int v = idx >> 9;
    int j = idx & (DETS - 1);

    float dImg = opt[4], dDet = opt[5], ang0 = opt[6], dAng = opt[7];
    float s2r = opt[8], d2r = opt[9], binshift = opt[10];

    float beta = ang0 + dAng * (float)v;
    float cb = cosf(beta), sb = sinf(beta);
    float u = ((float)j - (DETS - 1) * 0.5f) * dDet + binshift;

    float srcx = s2r * cb, srcy = s2r * sb;
    float dx = -d2r * cb - u * sb - srcx;
    float dy = -d2r * sb + u * cb - srcy;
    float inv = rsqrtf(dx * dx + dy * dy);
    dx *= inv; dy *= inv;

    float R  = 0.5f * sqrtf((float)(HH * HH + WW * WW)) * dImg;
    float dl = 2.0f * R / (float)NS;
    float t0 = s2r - R + 0.5f * dl;
    float invD = 1.0f / dImg;

    float px0 = (srcx + dx * t0) * invD + (WW - 1) * 0.5f;
    float py0 = (srcy + dy * t0) * invD + (HH - 1) * 0.5f;
    float sx = dx * dl * invD;
    float sy = dy * dl * invD;

    float acc0 = 0.0f, acc1 = 0.0f;
    for (int s = 0; s < NS; ++s) {
        float px = fmaf((float)s, sx, px0);
        float py = fmaf((float)s, sy, py0);
        if (px > -1.0f && px < (float)WW && py > -1.0f && py < (float)HH) {
            float x0 = floorf(px), y0 = floorf(py);
            float wx = px - x0, wy = py - y0;
            int x0i = (int)x0, y0i = (int)y0;
            int x1i = x0i + 1, y1i = y0i + 1;
            bool bx0 = (x0i >= 0), bx1 = (x1i <= WW - 1);
            bool by0 = (y0i >= 0), by1 = (y1i <= HH - 1);
            int xc0 = bx0 ? x0i : 0, xc1 = bx1 ? x1i : (WW - 1);
            int yc0 = by0 ? y0i : 0, yc1 = by1 ? y1i : (HH - 1);
            float w00 = (1.0f - wx) * (1.0f - wy);
            float w01 = wx * (1.0f - wy);
            float w10 = (1.0f - wx) * wy;
            float w11 = wx * wy;
            w00 = (bx0 & by0) ? w00 : 0.0f;
            w01 = (bx1 & by0) ? w01 : 0.0f;
            w10 = (bx0 & by1) ? w10 : 0.0f;
            w11 = (bx1 & by1) ? w11 : 0.0f;
            int r0 = yc0 * WW, r1 = yc1 * WW;
            const float* p0 = img;
            const float* p1 = img + HH * WW;
            acc0 = fmaf(w00, p0[r0 + xc0], acc0);
            acc0 = fmaf(w01, p0[r0 + xc1], acc0);
            acc0 = fmaf(w10, p0[r1 + xc0], acc0);
            acc0 = fmaf(w11, p0[r1 + xc1], acc0);
            acc1 = fmaf(w00, p1[r0 + xc0], acc1);
            acc1 = fmaf(w01, p1[r0 + xc1], acc1);
            acc1 = fmaf(w10, p1[r1 + xc0], acc1);
            acc1 = fmaf(w11, p1[r1 + xc1], acc1);
        }
    }
    int o = v * DETS + j;
    out[o] = acc0 * dl;
    out[VIEWS * DETS + o] = acc1 * dl;
}

extern "C" void kernel_launch(void* const* d_in, const int* in_sizes, int n_in,
                              void* d_out, int out_size, void* d_ws, size_t ws_size,
                              hipStream_t stream) {
    const float* img = (const float*)d_in[0];
    const float* opt = (const float*)d_in[1];
    float* out = (float*)d_out;

    size_t one = sizeof(uint4) * P * P;
    dim3 grid(16, VIEWS);   // 4 waves/block, det-group = blockIdx.x + 16*wave

    if (ws_size >= 2 * one) {
        uint4* N = (uint4*)d_ws;
        uint4* T = N + P * P;
        build_pack<<<(P * P + 255) / 256, 256, 0, stream>>>(img, N, T);
        project_pack<<<grid, 256, 0, stream>>>(N, T, 1, opt, out);
    } else if (ws_size >= one) {
        uint4* N = (uint4*)d_ws;
        build_pack<<<(P * P + 255) / 256, 256, 0, stream>>>(img, N, nullptr);
        project_pack<<<grid, 256, 0, stream>>>(N, N, 0, opt, out);
    } else {
        project_fallback<<<VIEWS * DETS / 256, 256, 0, stream>>>(img, opt, out);
    }
}

// Round 9
// 55.769 us; speedup vs baseline: 2.3587x; 1.1265x over previous
//
#include <hip/hip_runtime.h>

#define VIEWS 512
#define DETS  512
#define HH    256
#define WW    256
#define NS    384
#define P     264   // entry grid: entry[r][c] covers pixels (r-2..r-1, c-2..c-1); zero outside

typedef __fp16 h2 __attribute__((ext_vector_type(2)));
typedef _Float16 f16x2 __attribute__((ext_vector_type(2)));

__device__ inline h2 pkrtz(float a, float b) {
    return __builtin_amdgcn_cvt_pkrtz(a, b);
}

__device__ inline float dot2(h2 a, h2 b, float c) {
#if __has_builtin(__builtin_amdgcn_fdot2)
    union { h2 h; f16x2 f; } ua, ub;
    ua.h = a; ub.h = b;
    return __builtin_amdgcn_fdot2(ua.f, ub.f, c, false);
#else
    return fmaf((float)a.x, (float)b.x, fmaf((float)a.y, (float)b.y, c));
#endif
}

__device__ inline unsigned as_u(h2 h) { union { h2 h; unsigned u; } x; x.h = h; return x.u; }
__device__ inline h2 as_h2(unsigned u) { union { unsigned u; h2 h; } x; x.u = u; return x.h; }

// Entry (channel-major f16 pairs):
//   e.x = (v00c0, v01c0)   e.y = (v10c0, v11c0)
//   e.z = (v00c1, v01c1)   e.w = (v10c1, v11c1)
__global__ void build_pack(const float* __restrict__ img,
                           uint4* __restrict__ N, uint4* __restrict__ T) {
    int i = blockIdx.x * blockDim.x + threadIdx.x;
    if (i >= P * P) return;
    int r = i / P, c = i - r * P;
    int y = r - 2, x = c - 2;

    auto g = [&](int yy, int xx, int ch) -> float {
        return (xx >= 0 && xx < WW && yy >= 0 && yy < HH)
             ? img[ch * HH * WW + yy * WW + xx] : 0.0f;
    };

    uint4 e;
    e.x = as_u(pkrtz(g(y,     x, 0), g(y,     x + 1, 0)));
    e.y = as_u(pkrtz(g(y + 1, x, 0), g(y + 1, x + 1, 0)));
    e.z = as_u(pkrtz(g(y,     x, 1), g(y,     x + 1, 1)));
    e.w = as_u(pkrtz(g(y + 1, x, 1), g(y + 1, x + 1, 1)));
    N[i] = e;

    if (T) {
        // Timg(a,b) = img(b,a); entry covers Timg(y..y+1, x..x+1)
        uint4 t;
        t.x = as_u(pkrtz(g(x, y,     0), g(x + 1, y,     0)));
        t.y = as_u(pkrtz(g(x, y + 1, 0), g(x + 1, y + 1, 0)));
        t.z = as_u(pkrtz(g(x, y,     1), g(x + 1, y,     1)));
        t.w = as_u(pkrtz(g(x, y + 1, 1), g(x + 1, y + 1, 1)));
        T[i] = t;
    }
}

// Wave = 8 dets x 8 sample-slots; one dwordx4 gather + 4 fdot2 per sample.
// Wave w of block b handles det-group (b + 16*w): every block mixes center+edge work.
__global__ __launch_bounds__(256, 8) void project_pack(
    const uint4* __restrict__ imgN,
    const uint4* __restrict__ imgT,
    int allow_trans,
    const float* __restrict__ opt,
    float* __restrict__ out)
{
    int tid  = threadIdx.x;
    int wave = tid >> 6;
    int lane = tid & 63;
    int det_l = lane & 7;
    int slot  = lane >> 3;

    int det_base = (blockIdx.x + wave * 16) * 8;
    int j = det_base + det_l;
    int v = blockIdx.y;

    float dImg = opt[4], dDet = opt[5], ang0 = opt[6], dAng = opt[7];
    float s2r = opt[8], d2r = opt[9], binshift = opt[10];

    float beta = ang0 + dAng * (float)v;
    float cb = cosf(beta), sb = sinf(beta);
    float u = ((float)j - (DETS - 1) * 0.5f) * dDet + binshift;

    float srcx = s2r * cb, srcy = s2r * sb;
    float dx = -d2r * cb - u * sb - srcx;
    float dy = -d2r * sb + u * cb - srcy;
    float inv = rsqrtf(dx * dx + dy * dy);
    dx *= inv; dy *= inv;

    float R  = 0.5f * sqrtf((float)(HH * HH + WW * WW)) * dImg;
    float dl = 2.0f * R / (float)NS;
    float t0 = s2r - R + 0.5f * dl;
    float invD = 1.0f / dImg;

    float px0 = (srcx + dx * t0) * invD + (WW - 1) * 0.5f;
    float py0 = (srcy + dy * t0) * invD + (HH - 1) * 0.5f;
    float sx = dx * dl * invD;
    float sy = dy * dl * invD;

    // Pick orientation where det-spread is row-aligned (slope <= 1).
    bool trans = allow_trans && (fabsf(cb) > fabsf(sb));
    const uint4* img2 = trans ? imgT : imgN;
    if (trans) { float t = px0; px0 = py0; py0 = t; t = sx; sx = sy; sy = t; }

    // Analytic sample range; slack samples land in the zero border.
    float lo = 0.0f, hi = (float)(NS - 1);
    if (fabsf(sx) > 1e-7f) {
        float a = (-1.0f - px0) / sx, b = ((float)WW - px0) / sx;
        lo = fmaxf(lo, fminf(a, b)); hi = fminf(hi, fmaxf(a, b));
    } else if (!(px0 > -1.0f && px0 < (float)WW)) { lo = 1.0f; hi = 0.0f; }
    if (fabsf(sy) > 1e-7f) {
        float a = (-1.0f - py0) / sy, b = ((float)HH - py0) / sy;
        lo = fmaxf(lo, fminf(a, b)); hi = fminf(hi, fmaxf(a, b));
    } else if (!(py0 > -1.0f && py0 < (float)HH)) { lo = 1.0f; hi = 0.0f; }
    lo = fminf(fmaxf(lo, 0.0f), (float)NS);
    hi = fminf(fmaxf(hi, 0.0f), (float)NS);

    int s_begin = max((int)floorf(lo), 0);
    int s_end   = min((int)ceilf(hi) + 1, NS);

    float acc0 = 0.0f, acc1 = 0.0f;

    // Padded coords, incremental stepping (drift << tolerance).
    float fs0 = (float)(s_begin + slot);
    float pxp = fmaf(fs0, sx, px0) + 2.0f;
    float pyp = fmaf(fs0, sy, py0) + 2.0f;
    float sx8 = 8.0f * sx, sy8 = 8.0f * sy;

    #pragma unroll 2
    for (int s = s_begin + slot; s < s_end; s += 8) {
        float xf = floorf(pxp), yf = floorf(pyp);
        float wx = pxp - xf, wy = pyp - yf;
        int xi = min(max((int)xf, 0), P - 1);
        int yi = min(max((int)yf, 0), P - 1);

        uint4 e = img2[yi * P + xi];

        float ax = 1.0f - wx;
        h2 A = pkrtz(ax, wx);
        h2 B = pkrtz(1.0f - wy, 1.0f - wy);
        h2 C = pkrtz(wy, wy);
        h2 wr0 = A * B;   // (w00, w01)
        h2 wr1 = A * C;   // (w10, w11)

        acc0 = dot2(as_h2(e.x), wr0, acc0);
        acc0 = dot2(as_h2(e.y), wr1, acc0);
        acc1 = dot2(as_h2(e.z), wr0, acc1);
        acc1 = dot2(as_h2(e.w), wr1, acc1);

        pxp += sx8; pyp += sy8;
    }

    acc0 += __shfl_xor(acc0, 8);
    acc1 += __shfl_xor(acc1, 8);
    acc0 += __shfl_xor(acc0, 16);
    acc1 += __shfl_xor(acc1, 16);
    acc0 += __shfl_xor(acc0, 32);
    acc1 += __shfl_xor(acc1, 32);

    if (lane < 8) {
        int o = v * DETS + det_base + lane;
        out[o] = acc0 * dl;
        out[VIEWS * DETS + o] = acc1 * dl;
    }
}

// Fallback (ws too small): one thread per ray, planar loads, direct store.
__global__ __launch_bounds__(256) void project_fallback(
    const float* __restrict__ img,
    const float* __restrict__ opt,
    float* __restrict__ out)
{
    int idx = blockIdx.x * blockDim.x + threadIdx.x;
    int v = idx >> 9;
    int j = idx & (DETS - 1);

    float dImg = opt[4], dDet = opt[5], ang0 = opt[6], dAng = opt[7];
    float s2r = opt[8], d2r = opt[9], binshift = opt[10];

    float beta = ang0 + dAng * (float)v;
    float cb = cosf(beta), sb = sinf(beta);
    float u = ((float)j - (DETS - 1) * 0.5f) * dDet + binshift;

    float srcx = s2r * cb, srcy = s2r * sb;
    float dx = -d2r * cb - u * sb - srcx;
    float dy = -d2r * sb + u * cb - srcy;
    float inv = rsqrtf(dx * dx + dy * dy);
    dx *= inv; dy *= inv;

    float R  = 0.5f * sqrtf((float)(HH * HH + WW * WW)) * dImg;
    float dl = 2.0f * R / (float)NS;
    float t0 = s2r - R + 0.5f * dl;
    float invD = 1.0f / dImg;

    float px0 = (srcx + dx * t0) * invD + (WW - 1) * 0.5f;
    float py0 = (srcy + dy * t0) * invD + (HH - 1) * 0.5f;
    float sx = dx * dl * invD;
    float sy = dy * dl * invD;

    float acc0 = 0.0f, acc1 = 0.0f;
    for (int s = 0; s < NS; ++s) {
        float px = fmaf((float)s, sx, px0);
        float py = fmaf((float)s, sy, py0);
        if (px > -1.0f && px < (float)WW && py > -1.0f && py < (float)HH) {
            float x0 = floorf(px), y0 = floorf(py);
            float wx = px - x0, wy = py - y0;
            int x0i = (int)x0, y0i = (int)y0;
            int x1i = x0i + 1, y1i = y0i + 1;
            bool bx0 = (x0i >= 0), bx1 = (x1i <= WW - 1);
            bool by0 = (y0i >= 0), by1 = (y1i <= HH - 1);
            int xc0 = bx0 ? x0i : 0, xc1 = bx1 ? x1i : (WW - 1);
            int yc0 = by0 ? y0i : 0, yc1 = by1 ? y1i : (HH - 1);
            float w00 = (1.0f - wx) * (1.0f - wy);
            float w01 = wx * (1.0f - wy);
            float w10 = (1.0f - wx) * wy;
            float w11 = wx * wy;
            w00 = (bx0 & by0) ? w00 : 0.0f;
            w01 = (bx1 & by0) ? w01 : 0.0f;
            w10 = (bx0 & by1) ? w10 : 0.0f;
            w11 = (bx1 & by1) ? w11 : 0.0f;
            int r0 = yc0 * WW, r1 = yc1 * WW;
            const float* p0 = img;
            const float* p1 = img + HH * WW;
            acc0 = fmaf(w00, p0[r0 + xc0], acc0);
            acc0 = fmaf(w01, p0[r0 + xc1], acc0);
            acc0 = fmaf(w10, p0[r1 + xc0], acc0);
            acc0 = fmaf(w11, p0[r1 + xc1], acc0);
            acc1 = fmaf(w00, p1[r0 + xc0], acc1);
            acc1 = fmaf(w01, p1[r0 + xc1], acc1);
            acc1 = fmaf(w10, p1[r1 + xc0], acc1);
            acc1 = fmaf(w11, p1[r1 + xc1], acc1);
        }
    }
    int o = v * DETS + j;
    out[o] = acc0 * dl;
    out[VIEWS * DETS + o] = acc1 * dl;
}

extern "C" void kernel_launch(void* const* d_in, const int* in_sizes, int n_in,
                              void* d_out, int out_size, void* d_ws, size_t ws_size,
                              hipStream_t stream) {
    const float* img = (const float*)d_in[0];
    const float* opt = (const float*)d_in[1];
    float* out = (float*)d_out;

    size_t one = sizeof(uint4) * P * P;
    dim3 grid(16, VIEWS);   // 4 waves/block, det-group = blockIdx.x + 16*wave

    if (ws_size >= 2 * one) {
        uint4* N = (uint4*)d_ws;
        uint4* T = N + P * P;
        build_pack<<<(P * P + 255) / 256, 256, 0, stream>>>(img, N, T);
        project_pack<<<grid, 256, 0, stream>>>(N, T, 1, opt, out);
    } else if (ws_size >= one) {
        uint4* N = (uint4*)d_ws;
        build_pack<<<(P * P + 255) / 256, 256, 0, stream>>>(img, N, nullptr);
        project_pack<<<grid, 256, 0, stream>>>(N, N, 0, opt, out);
    } else {
        project_fallback<<<VIEWS * DETS / 256, 256, 0, stream>>>(img, opt, out);
    }
}

// Round 10
// 55.119 us; speedup vs baseline: 2.3865x; 1.0118x over previous
//
#include <hip/hip_runtime.h>

#define VIEWS 512
#define DETS  512
#define HH    256
#define WW    256
#define NS    384
#define P     258   // 1-ring pad: entry[r][c] covers pixels (r-1..r, c-1..c); zero outside

typedef __fp16 h2 __attribute__((ext_vector_type(2)));
typedef _Float16 f16x2 __attribute__((ext_vector_type(2)));

#if __has_builtin(__builtin_amdgcn_make_buffer_rsrc) && __has_builtin(__builtin_amdgcn_raw_buffer_load_b128)
#define USE_BUF 1
typedef unsigned u32x4 __attribute__((ext_vector_type(4)));
#else
#define USE_BUF 0
#endif

__device__ inline h2 pkrtz(float a, float b) {
    return __builtin_amdgcn_cvt_pkrtz(a, b);
}

__device__ inline float dot2(h2 a, h2 b, float c) {
#if __has_builtin(__builtin_amdgcn_fdot2)
    union { h2 h; f16x2 f; } ua, ub;
    ua.h = a; ub.h = b;
    return __builtin_amdgcn_fdot2(ua.f, ub.f, c, false);
#else
    return fmaf((float)a.x, (float)b.x, fmaf((float)a.y, (float)b.y, c));
#endif
}

__device__ inline unsigned as_u(h2 h) { union { h2 h; unsigned u; } x; x.h = h; return x.u; }
__device__ inline h2 as_h2(unsigned u) { union { unsigned u; h2 h; } x; x.u = u; return x.h; }

// Entry (channel-major f16 pairs):
//   e.x = (v00c0, v01c0)   e.y = (v10c0, v11c0)
//   e.z = (v00c1, v01c1)   e.w = (v10c1, v11c1)
__global__ void build_pack(const float* __restrict__ img,
                           uint4* __restrict__ N, uint4* __restrict__ T) {
    int i = blockIdx.x * blockDim.x + threadIdx.x;
    if (i >= P * P) return;
    int r = i / P, c = i - r * P;
    int y = r - 1, x = c - 1;

    auto g = [&](int yy, int xx, int ch) -> float {
        return (xx >= 0 && xx < WW && yy >= 0 && yy < HH)
             ? img[ch * HH * WW + yy * WW + xx] : 0.0f;
    };

    uint4 e;
    e.x = as_u(pkrtz(g(y,     x, 0), g(y,     x + 1, 0)));
    e.y = as_u(pkrtz(g(y + 1, x, 0), g(y + 1, x + 1, 0)));
    e.z = as_u(pkrtz(g(y,     x, 1), g(y,     x + 1, 1)));
    e.w = as_u(pkrtz(g(y + 1, x, 1), g(y + 1, x + 1, 1)));
    N[i] = e;

    if (T) {
        // Timg(a,b) = img(b,a); entry covers Timg(y..y+1, x..x+1)
        uint4 t;
        t.x = as_u(pkrtz(g(x, y,     0), g(x + 1, y,     0)));
        t.y = as_u(pkrtz(g(x, y + 1, 0), g(x + 1, y + 1, 0)));
        t.z = as_u(pkrtz(g(x, y,     1), g(x + 1, y,     1)));
        t.w = as_u(pkrtz(g(x, y + 1, 1), g(x + 1, y + 1, 1)));
        T[i] = t;
    }
}

// Wave = 8 dets x 8 sample-slots; one buffer_load_dwordx4 + 4 fdot2 per sample.
// Wave w of block b handles det-group (b + 16*w): every block mixes center+edge work.
// HW bounds-check (num_records) returns zeros for OOB entries == zero-pad semantics.
__global__ __launch_bounds__(256, 8) void project_pack(
    const uint4* __restrict__ imgN,
    const uint4* __restrict__ imgT,
    int allow_trans,
    const float* __restrict__ opt,
    float* __restrict__ out)
{
    int tid  = threadIdx.x;
    int wave = tid >> 6;
    int lane = tid & 63;
    int det_l = lane & 7;
    int slot  = lane >> 3;

    int det_base = (blockIdx.x + wave * 16) * 8;
    int j = det_base + det_l;
    int v = blockIdx.y;

    float dImg = opt[4], dDet = opt[5], ang0 = opt[6], dAng = opt[7];
    float s2r = opt[8], d2r = opt[9], binshift = opt[10];

    float beta = ang0 + dAng * (float)v;
    float cb = cosf(beta), sb = sinf(beta);
    float u = ((float)j - (DETS - 1) * 0.5f) * dDet + binshift;

    float srcx = s2r * cb, srcy = s2r * sb;
    float dx = -d2r * cb - u * sb - srcx;
    float dy = -d2r * sb + u * cb - srcy;
    float inv = rsqrtf(dx * dx + dy * dy);
    dx *= inv; dy *= inv;

    float R  = 0.5f * sqrtf((float)(HH * HH + WW * WW)) * dImg;
    float dl = 2.0f * R / (float)NS;
    float t0 = s2r - R + 0.5f * dl;
    float invD = 1.0f / dImg;

    float px0 = (srcx + dx * t0) * invD + (WW - 1) * 0.5f;
    float py0 = (srcy + dy * t0) * invD + (HH - 1) * 0.5f;
    float sx = dx * dl * invD;
    float sy = dy * dl * invD;

    // Pick orientation where det-spread is row-aligned (slope <= 1).
    bool trans = allow_trans && (fabsf(cb) > fabsf(sb));
    const uint4* img2 = trans ? imgT : imgN;
    if (trans) { float t = px0; px0 = py0; py0 = t; t = sx; sx = sy; sy = t; }

    // Analytic sample range; slack samples hit zero entries / OOB-zero loads.
    float lo = 0.0f, hi = (float)(NS - 1);
    if (fabsf(sx) > 1e-7f) {
        float a = (-1.0f - px0) / sx, b = ((float)WW - px0) / sx;
        lo = fmaxf(lo, fminf(a, b)); hi = fminf(hi, fmaxf(a, b));
    } else if (!(px0 > -1.0f && px0 < (float)WW)) { lo = 1.0f; hi = 0.0f; }
    if (fabsf(sy) > 1e-7f) {
        float a = (-1.0f - py0) / sy, b = ((float)HH - py0) / sy;
        lo = fmaxf(lo, fminf(a, b)); hi = fminf(hi, fmaxf(a, b));
    } else if (!(py0 > -1.0f && py0 < (float)HH)) { lo = 1.0f; hi = 0.0f; }
    lo = fminf(fmaxf(lo, 0.0f), (float)NS);
    hi = fminf(fmaxf(hi, 0.0f), (float)NS);

    int s_begin = max((int)floorf(lo), 0);
    int s_end   = min((int)ceilf(hi) + 1, NS);

    float acc0 = 0.0f, acc1 = 0.0f;

    // Padded coords, incremental stepping (drift << tolerance).
    float fs0 = (float)(s_begin + slot);
    float pxp = fmaf(fs0, sx, px0) + 1.0f;
    float pyp = fmaf(fs0, sy, py0) + 1.0f;
    float sx8 = 8.0f * sx, sy8 = 8.0f * sy;

#if USE_BUF
    __amdgpu_buffer_rsrc_t rsrc = __builtin_amdgcn_make_buffer_rsrc(
        (void*)img2, (short)0, (unsigned)(P * P * sizeof(uint4)), 0x00020000);
#endif

    #pragma unroll 2
    for (int s = s_begin + slot; s < s_end; s += 8) {
        float xf = floorf(pxp), yf = floorf(pyp);
        float wx = pxp - xf, wy = pyp - yf;
        int xi = (int)xf, yi = (int)yf;

        uint4 e;
#if USE_BUF
        unsigned voff = (unsigned)((yi * P + xi) * (int)sizeof(uint4));
        u32x4 q = __builtin_amdgcn_raw_buffer_load_b128(rsrc, voff, 0, 0);
        e.x = q.x; e.y = q.y; e.z = q.z; e.w = q.w;
#else
        int xc = min(max(xi, 0), P - 1);
        int yc = min(max(yi, 0), P - 1);
        e = img2[yc * P + xc];
#endif

        h2 A  = pkrtz(1.0f - wx, wx);
        h2 BC = pkrtz(1.0f - wy, wy);
        h2 wr0 = A * BC.xx;   // (w00, w01)
        h2 wr1 = A * BC.yy;   // (w10, w11)

        acc0 = dot2(as_h2(e.x), wr0, acc0);
        acc0 = dot2(as_h2(e.y), wr1, acc0);
        acc1 = dot2(as_h2(e.z), wr0, acc1);
        acc1 = dot2(as_h2(e.w), wr1, acc1);

        pxp += sx8; pyp += sy8;
    }

    acc0 += __shfl_xor(acc0, 8);
    acc1 += __shfl_xor(acc1, 8);
    acc0 += __shfl_xor(acc0, 16);
    acc1 += __shfl_xor(acc1, 16);
    acc0 += __shfl_xor(acc0, 32);
    acc1 += __shfl_xor(acc1, 32);

    if (lane < 8) {
        int o = v * DETS + det_base + lane;
        out[o] = acc0 * dl;
        out[VIEWS * DETS + o] = acc1 * dl;
    }
}

// Fallback (ws too small): one thread per ray, planar loads, direct store.
__global__ __launch_bounds__(256) void project_fallback(
    const float* __restrict__ img,
    const float* __restrict__ opt,
    float* __restrict__ out)
{
    int idx = blockIdx.x * blockDim.x + threadIdx.x;
    int v = idx >> 9;
    int j = idx & (DETS - 1);

    float dImg = opt[4], dDet = opt[5], ang0 = opt[6], dAng = opt[7];
    float s2r = opt[8], d2r = opt[9], binshift = opt[10];

    float beta = ang0 + dAng * (float)v;
    float cb = cosf(beta), sb = sinf(beta);
    float u = ((float)j - (DETS - 1) * 0.5f) * dDet + binshift;

    float srcx = s2r * cb, srcy = s2r * sb;
    float dx = -d2r * cb - u * sb - srcx;
    float dy = -d2r * sb + u * cb - srcy;
    float inv = rsqrtf(dx * dx + dy * dy);
    dx *= inv; dy *= inv;

    float R  = 0.5f * sqrtf((float)(HH * HH + WW * WW)) * dImg;
    float dl = 2.0f * R / (float)NS;
    float t0 = s2r - R + 0.5f * dl;
    float invD = 1.0f / dImg;

    float px0 = (srcx + dx * t0) * invD + (WW - 1) * 0.5f;
    float py0 = (srcy + dy * t0) * invD + (HH - 1) * 0.5f;
    float sx = dx * dl * invD;
    float sy = dy * dl * invD;

    float acc0 = 0.0f, acc1 = 0.0f;
    for (int s = 0; s < NS; ++s) {
        float px = fmaf((float)s, sx, px0);
        float py = fmaf((float)s, sy, py0);
        if (px > -1.0f && px < (float)WW && py > -1.0f && py < (float)HH) {
            float x0 = floorf(px), y0 = floorf(py);
            float wx = px - x0, wy = py - y0;
            int x0i = (int)x0, y0i = (int)y0;
            int x1i = x0i + 1, y1i = y0i + 1;
            bool bx0 = (x0i >= 0), bx1 = (x1i <= WW - 1);
            bool by0 = (y0i >= 0), by1 = (y1i <= HH - 1);
            int xc0 = bx0 ? x0i : 0, xc1 = bx1 ? x1i : (WW - 1);
            int yc0 = by0 ? y0i : 0, yc1 = by1 ? y1i : (HH - 1);
            float w00 = (1.0f - wx) * (1.0f - wy);
            float w01 = wx * (1.0f - wy);
            float w10 = (1.0f - wx) * wy;
            float w11 = wx * wy;
            w00 = (bx0 & by0) ? w00 : 0.0f;
            w01 = (bx1 & by0) ? w01 : 0.0f;
            w10 = (bx0 & by1) ? w10 : 0.0f;
            w11 = (bx1 & by1) ? w11 : 0.0f;
            int r0 = yc0 * WW, r1 = yc1 * WW;
            const float* p0 = img;
            const float* p1 = img + HH * WW;
            acc0 = fmaf(w00, p0[r0 + xc0], acc0);
            acc0 = fmaf(w01, p0[r0 + xc1], acc0);
            acc0 = fmaf(w10, p0[r1 + xc0], acc0);
            acc0 = fmaf(w11, p0[r1 + xc1], acc0);
            acc1 = fmaf(w00, p1[r0 + xc0], acc1);
            acc1 = fmaf(w01, p1[r0 + xc1], acc1);
            acc1 = fmaf(w10, p1[r1 + xc0], acc1);
            acc1 = fmaf(w11, p1[r1 + xc1], acc1);
        }
    }
    int o = v * DETS + j;
    out[o] = acc0 * dl;
    out[VIEWS * DETS + o] = acc1 * dl;
}

extern "C" void kernel_launch(void* const* d_in, const int* in_sizes, int n_in,
                              void* d_out, int out_size, void* d_ws, size_t ws_size,
                              hipStream_t stream) {
    const float* img = (const float*)d_in[0];
    const float* opt = (const float*)d_in[1];
    float* out = (float*)d_out;

    size_t one = sizeof(uint4) * P * P;
    dim3 grid(16, VIEWS);   // 4 waves/block, det-group = blockIdx.x + 16*wave

    if (ws_size >= 2 * one) {
        uint4* N = (uint4*)d_ws;
        uint4* T = N + P * P;
        build_pack<<<(P * P + 255) / 256, 256, 0, stream>>>(img, N, T);
        project_pack<<<grid, 256, 0, stream>>>(N, T, 1, opt, out);
    } else if (ws_size >= one) {
        uint4* N = (uint4*)d_ws;
        build_pack<<<(P * P + 255) / 256, 256, 0, stream>>>(img, N, nullptr);
        project_pack<<<grid, 256, 0, stream>>>(N, N, 0, opt, out);
    } else {
        project_fallback<<<VIEWS * DETS / 256, 256, 0, stream>>>(img, opt, out);
    }
}